// Round 2
// baseline (307.867 us; speedup 1.0000x reference)
//
#include <hip/hip_runtime.h>
#include <stdint.h>

#define LATENT 10
#define MAXLEN 80
#define STEPS  10
#define HIDDEN 32
#define BATCH  512

// ---------------------------------------------------------------------------
// Threefry-2x32, 20 rounds — bit-exact replica of jax threefry2x32_p.
// ---------------------------------------------------------------------------
__device__ __forceinline__ void tf2x32(uint32_t k0, uint32_t k1,
                                       uint32_t x0, uint32_t x1,
                                       uint32_t& o0, uint32_t& o1) {
  uint32_t ks2 = k0 ^ k1 ^ 0x1BD11BDAu;
  uint32_t v0 = x0 + k0;
  uint32_t v1 = x1 + k1;
#define TF_R(rot) { v0 += v1; v1 = (v1 << (rot)) | (v1 >> (32 - (rot))); v1 ^= v0; }
  TF_R(13) TF_R(15) TF_R(26) TF_R(6)
  v0 += k1;  v1 += ks2 + 1u;
  TF_R(17) TF_R(29) TF_R(16) TF_R(24)
  v0 += ks2; v1 += k0 + 2u;
  TF_R(13) TF_R(15) TF_R(26) TF_R(6)
  v0 += k0;  v1 += k1 + 3u;
  TF_R(17) TF_R(29) TF_R(16) TF_R(24)
  v0 += k1;  v1 += ks2 + 4u;
  TF_R(13) TF_R(15) TF_R(26) TF_R(6)
  v0 += ks2; v1 += k0 + 5u;
#undef TF_R
  o0 = v0; o1 = v1;
}

// JAX uniform(-0.99999994, 1) bits -> sqrt(2)*erfinv(u)  (XLA Giles polynomial)
__device__ __forceinline__ float bits_to_normal(uint32_t bits) {
  const float lo = -0.99999994f;                                 // nextafter(-1, 0)
  float f = __uint_as_float((bits >> 9) | 0x3f800000u) - 1.0f;   // [0,1)
  float u = fmaf(f, 2.0f, lo);                                   // (hi-lo) rounds to 2.0f
  u = fmaxf(u, lo);
  float w = -log1pf(-u * u);
  float p;
  if (w < 5.0f) {
    w -= 2.5f;
    p = 2.81022636e-08f;
    p = fmaf(p, w, 3.43273939e-07f);
    p = fmaf(p, w, -3.5233877e-06f);
    p = fmaf(p, w, -4.39150654e-06f);
    p = fmaf(p, w, 0.00021858087f);
    p = fmaf(p, w, -0.00125372503f);
    p = fmaf(p, w, -0.00417768164f);
    p = fmaf(p, w, 0.246640727f);
    p = fmaf(p, w, 1.50140941f);
  } else {
    w = sqrtf(w) - 3.0f;
    p = -0.000200214257f;
    p = fmaf(p, w, 0.000100950558f);
    p = fmaf(p, w, 0.00134934322f);
    p = fmaf(p, w, -0.00367342844f);
    p = fmaf(p, w, 0.00573950773f);
    p = fmaf(p, w, -0.0076224613f);
    p = fmaf(p, w, 0.00943887047f);
    p = fmaf(p, w, 1.00167406f);
    p = fmaf(p, w, 2.83297682f);
  }
  return 1.4142135623730951f * (p * u);
}

// ---------------------------------------------------------------------------
// Partitionable-threefry normal draw (jax_threefry_partitionable=True):
//   subkey m = both lanes of tf(key=(0,1337), x=(0, m))          [split foldlike]
//   bits(f)  = o0 ^ o1 of tf(subkey, x=(0, f)), f = linear index [random_bits]
// ---------------------------------------------------------------------------
struct NPPart {
  int i, b;
  __device__ __forceinline__ void draw(int kidx, float n[LATENT]) const {
    uint32_t a, c;
    tf2x32(0u, 1337u, 0u, (uint32_t)(i * (STEPS + 1) + kidx), a, c);
#pragma unroll
    for (int d = 0; d < LATENT; ++d) {
      uint32_t o0, o1;
      tf2x32(a, c, 0u, (uint32_t)(b * LATENT + d), o0, o1);
      n[d] = bits_to_normal(o0 ^ o1);
    }
  }
};

// ---------------------------------------------------------------------------
// One thread per (i, b): prefix + 10-step diffusion chain.
// ---------------------------------------------------------------------------
__global__ __launch_bounds__(64) void k_mono(
    const float* __restrict__ zmean, const float* __restrict__ zlv,
    const float* __restrict__ W1, const float* __restrict__ b1v,
    const float* __restrict__ W2, const float* __restrict__ b2v,
    float* __restrict__ outSeq, float* __restrict__ outErr) {
  int i = blockIdx.x >> 3;                       // wave-uniform
  int b = ((blockIdx.x & 7) << 6) + threadIdx.x; // 0..511

  // prefix[j] = sum_{l<i} mu[b,l,:] . W1[l*10 : l*10+10, j]
  float pref[HIDDEN];
#pragma unroll
  for (int j = 0; j < HIDDEN; ++j) pref[j] = 0.0f;
  for (int l = 0; l < i; ++l) {
    const float* mrow = zmean + (b * MAXLEN + l) * LATENT;
    const float* wrow = W1 + (l * LATENT) * HIDDEN;
#pragma unroll
    for (int d = 0; d < LATENT; ++d) {
      float m = mrow[d];
#pragma unroll
      for (int j = 0; j < HIDDEN; ++j) pref[j] = fmaf(m, wrow[d * HIDDEN + j], pref[j]);
    }
  }

  const int base = (b * MAXLEN + i) * LATENT;
  float mu[LATENT], sstd[LATENT], xt[LATENT], errs[LATENT];
#pragma unroll
  for (int d = 0; d < LATENT; ++d) {
    mu[d] = zmean[base + d];
    sstd[d] = sqrtf(expf(zlv[base + d]));
  }
  NPPart np_{i, b};
  float n0[LATENT];
  np_.draw(0, n0);
#pragma unroll
  for (int d = 0; d < LATENT; ++d) { xt[d] = mu[d] + sstd[d] * n0[d]; errs[d] = 0.0f; }

  const float* rowT  = W1 + (MAXLEN * LATENT) * HIDDEN;  // time row (k=800)
  const float* rowsI = W1 + (i * LATENT) * HIDDEN;       // xt rows
  const float SQRT_DT = sqrtf(0.1f);

  for (int s = 0; s < STEPS; ++s) {
    float t = (float)i + (float)s * 0.1f;
    float h[HIDDEN];
#pragma unroll
    for (int j = 0; j < HIDDEN; ++j) h[j] = pref[j];
#pragma unroll
    for (int d = 0; d < LATENT; ++d) {
      float xd = xt[d];
      const float* row = rowsI + d * HIDDEN;
#pragma unroll
      for (int j = 0; j < HIDDEN; ++j) h[j] = fmaf(xd, row[j], h[j]);
    }
    float sc[LATENT];
#pragma unroll
    for (int d = 0; d < LATENT; ++d) sc[d] = b2v[d];
#pragma unroll
    for (int j = 0; j < HIDDEN; ++j) {
      float hj = fmaf(t, rowT[j], h[j]) + b1v[j];
      hj = fmaxf(hj, 0.0f);
      const float* w2r = W2 + j * LATENT;
#pragma unroll
      for (int d = 0; d < LATENT; ++d) sc[d] = fmaf(hj, w2r[d], sc[d]);
    }
    float nd[LATENT];
    np_.draw(s + 1, nd);
#pragma unroll
    for (int d = 0; d < LATENT; ++d) {
      float logdx = -(xt[d] - mu[d]) / sstd[d];
      errs[d] += fabsf(logdx - sc[d]);
      float dW = nd[d] * SQRT_DT;
      xt[d] = xt[d] + (0.5f * (sstd[d] * sstd[d])) * sc[d] + sstd[d] * dW;
    }
  }
#pragma unroll
  for (int d = 0; d < LATENT; ++d) {
    outSeq[base + d] = xt[d];
    outErr[base + d] = errs[d];
  }
}

// ---------------------------------------------------------------------------
extern "C" void kernel_launch(void* const* d_in, const int* in_sizes, int n_in,
                              void* d_out, int out_size, void* d_ws, size_t ws_size,
                              hipStream_t stream) {
  (void)in_sizes; (void)n_in; (void)d_ws; (void)ws_size; (void)out_size;
  const float* zmean = (const float*)d_in[0];
  const float* zlv   = (const float*)d_in[1];
  const float* W1    = (const float*)d_in[2];
  const float* b1v   = (const float*)d_in[3];
  const float* W2    = (const float*)d_in[4];
  const float* b2v   = (const float*)d_in[5];
  float* outSeq = (float*)d_out;
  float* outErr = outSeq + (size_t)BATCH * MAXLEN * LATENT;

  hipLaunchKernelGGL(k_mono, dim3(MAXLEN * 8), dim3(64), 0, stream,
                     zmean, zlv, W1, b1v, W2, b2v, outSeq, outErr);
}